// Round 12
// baseline (330.945 us; speedup 1.0000x reference)
//
#include <hip/hip_runtime.h>

typedef unsigned short u16;
typedef __attribute__((ext_vector_type(8))) short short8;
typedef __attribute__((ext_vector_type(4))) float f32x4;

#define N_TOK 16384
#define DIN   1024
#define NE    16
#define DEMB  128
#define H1N   1024
#define H2N   512
#define DOUT  512
#define CAP   36864   // 32768 entries + 16*256 padding (256-aligned segments)
#define RBLK  1024    // router blocks (16 tokens each)

// ---- workspace layout (bytes), ends 168,657,408 (< proven 201.9 MB) ----
#define OFF_P      0ul           // 65536
#define OFF_C      65536ul       // 256
#define OFF_CTRL   65792ul       // counts[16]@0, poff[17]@128 (256)
#define OFF_E01    66048ul       // 131072
#define OFF_G01    197120ul      // 131072
#define OFF_GTOK   328192ul      // CAP*4 = 147456
#define OFF_GGATE  475648ul      // 147456
#define OFF_TSLOT  623104ul      // 131072
#define OFF_BH     754176ul      // 65536
#define OFF_BB     819712ul      // 65536
#define OFF_W2T    885248ul      // 16777216
#define OFF_W3T    17662464ul    // 8388608
#define OFF_W1T    26051072ul    // 33554432
#define OFF_XBF    59605504ul    // N_TOK*1024*2 = 33554432
#define OFF_H1     93159936ul    // CAP*1024*2 = 75497472
// aliases (disjoint lifetimes on the serial stream):
#define OFF_EO     OFF_H1        // eo f32 CAP*512*4 (h1 dead after L2)
#define OFF_H2     OFF_W1T       // h2 CAP*512*2 over W1T+XBF-head (dead after L1)

__device__ __forceinline__ u16 f2bf(float f) {
  union { float f; unsigned u; } v; v.f = f;
  unsigned r = v.u + 0x7fff + ((v.u >> 16) & 1);   // RNE, finite inputs
  return (u16)(r >> 16);
}

__device__ __forceinline__ void async_copy16(const u16* g, u16* l) {
  __builtin_amdgcn_global_load_lds((const __attribute__((address_space(1))) unsigned*)g,
                                   (__attribute__((address_space(3))) unsigned*)l,
                                   16, 0, 0);
}

// ---- K0: P = 2*Wr@emb^T [1024][16], c_e = 2*br.emb_e - |emb_e|^2 ----
__global__ void router_prep(const float* __restrict__ Wr, const float* __restrict__ br,
                            const float* __restrict__ emb, float* __restrict__ P,
                            float* __restrict__ c) {
  int idx = blockIdx.x * 256 + threadIdx.x;
  int row = idx >> 4, e = idx & 15;
  float s = 0.f;
  for (int j = 0; j < DEMB; ++j) s += Wr[row * DEMB + j] * emb[e * DEMB + j];
  P[row * NE + e] = 2.f * s;
  if (idx < NE) {
    float cc = 0.f, n2 = 0.f;
    for (int j = 0; j < DEMB; ++j) {
      float ev = emb[idx * DEMB + j];
      cc += br[j] * ev;
      n2 += ev * ev;
    }
    c[idx] = 2.f * cc - n2;
  }
}

// ---- K1: scores, top-2, gates; per-block LDS histogram -> bhist; xbf emit ----
__global__ void __launch_bounds__(256) router_score(
    const float* __restrict__ x, const float* __restrict__ P,
    const float* __restrict__ c, int* __restrict__ e01,
    float* __restrict__ g01, int* __restrict__ bhist,
    u16* __restrict__ xbf) {
  __shared__ float xs[16384];
  __shared__ int lh[16];
  int wave = threadIdx.x >> 6, lane = threadIdx.x & 63;
  int e2 = lane & 7, kgl = lane >> 3;
  int tbase = blockIdx.x * 16 + wave * 4;
  float* xw = xs + wave * 4096;

  if (threadIdx.x < 16) lh[threadIdx.x] = 0;

  u16* xbrow = xbf + (size_t)tbase * DIN;
  #pragma unroll
  for (int t = 0; t < 4; ++t) {
    const float* src = x + (size_t)(tbase + t) * DIN;
    #pragma unroll
    for (int q = 0; q < 4; ++q) {
      int g = q * 256 + lane * 4;
      float4 v = *(const float4*)(src + g);
      *(float4*)(xw + t * 1024 + g) = v;
      ushort4 o;
      o.x = f2bf(v.x); o.y = f2bf(v.y); o.z = f2bf(v.z); o.w = f2bf(v.w);
      *(ushort4*)(xbrow + t * DIN + g) = o;
    }
  }
  __syncthreads();

  int te0 = 2 * e2, te1 = te0 + 1;
  float ce0 = c[te0], ce1 = c[te1];
  const float* Pb = P + te0;

  float acc0[4] = {0.f, 0.f, 0.f, 0.f};
  float acc1[4] = {0.f, 0.f, 0.f, 0.f};
  int cbase = kgl * 128;
  #pragma unroll 4
  for (int i = 0; i < 32; ++i) {
    int w = (kgl * 4 + i * 4) & 127;
    int idx = cbase + w;
    float2 pv0 = *(const float2*)(Pb + (size_t)(idx + 0) * NE);
    float2 pv1 = *(const float2*)(Pb + (size_t)(idx + 1) * NE);
    float2 pv2 = *(const float2*)(Pb + (size_t)(idx + 2) * NE);
    float2 pv3 = *(const float2*)(Pb + (size_t)(idx + 3) * NE);
    #pragma unroll
    for (int t = 0; t < 4; ++t) {
      float4 xv = *(const float4*)(xw + t * 1024 + idx);
      acc0[t] = fmaf(xv.x, pv0.x, acc0[t]); acc1[t] = fmaf(xv.x, pv0.y, acc1[t]);
      acc0[t] = fmaf(xv.y, pv1.x, acc0[t]); acc1[t] = fmaf(xv.y, pv1.y, acc1[t]);
      acc0[t] = fmaf(xv.z, pv2.x, acc0[t]); acc1[t] = fmaf(xv.z, pv2.y, acc1[t]);
      acc0[t] = fmaf(xv.w, pv3.x, acc0[t]); acc1[t] = fmaf(xv.w, pv3.y, acc1[t]);
    }
  }

  for (int t = 0; t < 4; ++t) {
    float s0 = acc0[t], s1 = acc1[t];
    #pragma unroll
    for (int off = 8; off <= 32; off <<= 1) {
      s0 += __shfl_xor(s0, off);
      s1 += __shfl_xor(s1, off);
    }
    s0 += ce0; s1 += ce1;
    float hi; int hidx;
    if (s0 >= s1) { hi = s0; hidx = te0; } else { hi = s1; hidx = te1; }
    float m1 = hi; int i1 = hidx;
    #pragma unroll
    for (int off = 1; off < 8; off <<= 1) {
      float so = __shfl_xor(m1, off); int io = __shfl_xor(i1, off);
      if (so > m1 || (so == m1 && io < i1)) { m1 = so; i1 = io; }
    }
    float c2; int c2i;
    if (i1 == te0)      { c2 = s1; c2i = te1; }
    else if (i1 == te1) { c2 = s0; c2i = te0; }
    else                { c2 = hi; c2i = hidx; }
    float m2 = c2; int i2 = c2i;
    #pragma unroll
    for (int off = 1; off < 8; off <<= 1) {
      float so = __shfl_xor(m2, off); int io = __shfl_xor(i2, off);
      if (so > m2 || (so == m2 && io < i2)) { m2 = so; i2 = io; }
    }
    if (lane == 0) {
      int tok = tbase + t;
      float ev = expf(m2 - m1);
      float inv = 1.f / (1.f + ev);
      e01[tok * 2 + 0] = i1; e01[tok * 2 + 1] = i2;
      g01[tok * 2 + 0] = inv; g01[tok * 2 + 1] = ev * inv;
      atomicAdd(&lh[i1], 1);
      atomicAdd(&lh[i2], 1);
    }
  }
  __syncthreads();
  if (threadIdx.x < 16) bhist[blockIdx.x * 16 + threadIdx.x] = lh[threadIdx.x];
}

// ---- K2: scan bhist -> counts, poff (256-aligned), bases; zero-fill gtok pads ----
__global__ void __launch_bounds__(1024) scan_offsets(
    const int* __restrict__ bhist, int* __restrict__ counts,
    int* __restrict__ poff, int* __restrict__ bbase, int* __restrict__ gtok) {
  int t = threadIdx.x;
  int e = t & 15, ch = t >> 4;
  int b0 = ch * 16;
  int s = 0;
  #pragma unroll
  for (int i = 0; i < 16; ++i) s += bhist[(b0 + i) * 16 + e];
  __shared__ int part[64][16];
  __shared__ int chbase[64][16];
  __shared__ int cnt[16];
  __shared__ int pof[16];
  part[ch][e] = s;
  __syncthreads();
  if (t < 16) {
    int run = 0;
    for (int c2 = 0; c2 < 64; ++c2) { chbase[c2][t] = run; run += part[c2][t]; }
    cnt[t] = run;
  }
  __syncthreads();
  if (t == 0) {
    int off = 0;
    for (int e2 = 0; e2 < NE; ++e2) {
      pof[e2] = off;
      poff[e2] = off;
      counts[e2] = cnt[e2];
      off += (cnt[e2] + 255) & ~255;
    }
    poff[NE] = off;
  }
  __syncthreads();
  // zero-fill intra-expert pad slots of gtok (GEMM indirection reads them; token 0 safe)
  int padc = ((cnt[e] + 255) & ~255) - cnt[e];
  int pbase = pof[e] + cnt[e];
  for (int i = ch; i < padc; i += 64) gtok[pbase + i] = 0;

  int run = pof[e] + chbase[ch][e];
  #pragma unroll
  for (int i = 0; i < 16; ++i) {
    bbase[(b0 + i) * 16 + e] = run;
    run += bhist[(b0 + i) * 16 + e];
  }
}

// ---- K3: CSR entry lists + inverse map tslot[t*2+k] = slot ----
__global__ void build_lists(const int* __restrict__ e01, const float* __restrict__ g01,
                            const int* __restrict__ bbase, int* __restrict__ gtok,
                            float* __restrict__ ggate, int* __restrict__ tslot) {
  __shared__ int pos[16];
  int tid = threadIdx.x;
  if (tid < 16) pos[tid] = bbase[blockIdx.x * 16 + tid];
  __syncthreads();
  if (tid < 16) {
    int t = blockIdx.x * 16 + tid;
    #pragma unroll
    for (int k = 0; k < 2; ++k) {
      int e = e01[t * 2 + k];
      int p = atomicAdd(&pos[e], 1);
      gtok[p] = t;
      ggate[p] = g01[t * 2 + k];
      tslot[t * 2 + k] = p;
    }
  }
}

// ---- K5: weight convert+transpose: [E][K][N] f32 -> [E][N][K] bf16 ----
template<int K, int N>
__global__ void conv_w(const float* __restrict__ W, u16* __restrict__ WT) {
  __shared__ float tile[64][65];
  int e = blockIdx.z;
  int n0 = blockIdx.x * 64, k0 = blockIdx.y * 64;
  int tx = threadIdx.x & 63, ty = threadIdx.x >> 6;
  const float* Wb = W + (size_t)e * K * N;
  #pragma unroll
  for (int p = 0; p < 16; ++p) {
    int k = p * 4 + ty;
    tile[k][tx] = Wb[(size_t)(k0 + k) * N + n0 + tx];
  }
  __syncthreads();
  u16* WTb = WT + (size_t)e * N * K;
  #pragma unroll
  for (int p = 0; p < 16; ++p) {
    int n = p * 4 + ty;
    WTb[(size_t)(n0 + n) * K + k0 + tx] = f2bf(tile[tx][n]);
  }
}

// ======== 8-phase 256x256 MoE GEMM (T1+T2+T3+T4+T5), re-derived ========
// 8 waves (2Mx4N), BK=64; buf0=even K-tiles, buf1=odd. Phases = wave C-quadrants.
// ds_reads/phase: 12/4/8/0 (av reused lo->hi; bvlo lives ph1->ph4).
// Stage order (last-read-derived): ph1:Alo1 ph2:Ahi1 ph3:Blo0' ph4:Bhi0'
// ph5:Alo0' ph6:Ahi0' ph7:Blo1' ph8:Bhi1'. vmcnt(4) at ph4 (completes buf1)
// and ph8 (completes buf0) ONLY; 4-12 loads always in flight.
// LDS linear per lane (m104); swizzle on GLOBAL chunk (l&7)^(l>>3), read XOR
// (ks*4+kq)^(fr&7) -> 2 lanes/bank (free).
#define BAR  __builtin_amdgcn_s_barrier()
#define VW4  asm volatile("s_waitcnt vmcnt(4)" ::: "memory")

#define LOAD_A(BUF, HM) { _Pragma("unroll") for (int m = 0; m < 4; ++m) { \
    const u16* p_ = &Abuf[BUF][(wm * 128 + (HM) * 64 + m * 16 + fr) * 64]; \
    av[m][0] = *(const short8*)(p_ + ((kq ^ swz3) << 3)); \
    av[m][1] = *(const short8*)(p_ + (((4 + kq) ^ swz3) << 3)); } }

#define LOAD_B(BV, BUF, HN) { _Pragma("unroll") for (int n = 0; n < 2; ++n) { \
    const u16* p_ = &Bbuf[BUF][(wn * 64 + (HN) * 32 + n * 16 + fr) * 64]; \
    BV[n][0] = *(const short8*)(p_ + ((kq ^ swz3) << 3)); \
    BV[n][1] = *(const short8*)(p_ + (((4 + kq) ^ swz3) << 3)); } }

#define PH_MFMA(ACC, BV) { __builtin_amdgcn_s_setprio(1); \
  _Pragma("unroll") for (int m = 0; m < 4; ++m) \
  _Pragma("unroll") for (int n = 0; n < 2; ++n) { \
    ACC[m][n] = __builtin_amdgcn_mfma_f32_16x16x32_bf16(av[m][0], BV[n][0], ACC[m][n], 0, 0, 0); \
    ACC[m][n] = __builtin_amdgcn_mfma_f32_16x16x32_bf16(av[m][1], BV[n][1], ACC[m][n], 0, 0, 0); } \
  __builtin_amdgcn_s_setprio(0); }

#define EPI(ACC, RO, CO) { _Pragma("unroll") for (int m = 0; m < 4; ++m) { \
    int gr0 = row_base + wm * 128 + (RO) + m * 16 + crow; \
    _Pragma("unroll") for (int n = 0; n < 2; ++n) { \
      int gc = n_base + wn * 64 + (CO) + n * 16 + ccol; \
      float bvs = be[gc]; \
      _Pragma("unroll") for (int r2 = 0; r2 < 4; ++r2) { \
        if constexpr (MODE == 0) { \
          float v = ACC[m][n][r2] + bvs; v = v > 0.f ? v : 0.f; \
          Cb[(size_t)(gr0 + r2) * N + gc] = f2bf(v); \
        } else { \
          outF[(size_t)(gr0 + r2) * N + gc] = ACC[m][n][r2] + bvs; } } } } }

template<int MODE, bool INDIR>
__global__ void __launch_bounds__(512)
gemm_moe256(const u16* __restrict__ A, const u16* __restrict__ Ball,
            const float* __restrict__ bias, u16* __restrict__ Cb,
            float* __restrict__ outF, const int* __restrict__ poff,
            const int* __restrict__ gtok, int K, int N, int nblk) {
  __shared__ u16 Abuf[2][16384];   // [256 rows][64 k]
  __shared__ u16 Bbuf[2][16384];

  // T1: bijective XCD remap, nb-fastest
  int bid = blockIdx.x;
  int q8 = nblk >> 3, r8 = nblk & 7;
  int xcd = bid & 7, sidx = bid >> 3;
  int wg = (xcd < r8 ? xcd * (q8 + 1) : r8 * (q8 + 1) + (xcd - r8) * q8) + sidx;
  int NB = N >> 8;
  int rb = wg / NB, nb = wg - rb * NB;
  int row_base = rb * 256;
  if (row_base >= poff[NE]) return;
  int e = 0;
  while (row_base >= poff[e + 1]) ++e;

  int tid = threadIdx.x;               // 0..511
  int lane = tid & 63, wv = tid >> 6;  // 8 waves
  int wm = wv >> 2, wn = wv & 3;       // 2M x 4N; wave tile 128x64
  int fr = lane & 15, kq = lane >> 4;
  int swz3 = fr & 7;
  int n_base = nb * 256;

  // staging roles: wave wv covers rows wv*16..wv*16+15 of each half;
  // lane l -> row group l>>3 (j adds 8), chunk slot l&7, src chunk (l&7)^(l>>3)
  int l8 = (tid >> 3) & 7;
  int rbase = ((tid >> 6) << 4) + l8;  // row-in-half for j=0 (0..127 over waves)
  int csrc = ((tid & 7) ^ l8) << 3;    // source chunk offset (u16)

  const u16 *pA[2][2], *pB[2][2];
  const u16* Bexp = Ball + (size_t)e * N * K;
  #pragma unroll
  for (int h = 0; h < 2; ++h)
    #pragma unroll
    for (int j = 0; j < 2; ++j) {
      int row = h * 128 + rbase + j * 8;
      if constexpr (INDIR) pA[h][j] = A + (size_t)gtok[row_base + row] * K;
      else                 pA[h][j] = A + (size_t)(row_base + row) * K;
      pB[h][j] = Bexp + (size_t)(n_base + row) * K;
    }

  int ldst = ((tid >> 6) << 10) + ((tid & 63) << 3);  // lane-linear (u16)

  auto stA = [&](int buf, int h, int kt) {
    u16* l0 = &Abuf[buf][h * 8192 + ldst];
    async_copy16(pA[h][0] + kt + csrc, l0);
    async_copy16(pA[h][1] + kt + csrc, l0 + 512);
  };
  auto stB = [&](int buf, int h, int kt) {
    u16* l0 = &Bbuf[buf][h * 8192 + ldst];
    async_copy16(pB[h][0] + kt + csrc, l0);
    async_copy16(pB[h][1] + kt + csrc, l0 + 512);
  };

  f32x4 q00[4][2], q01[4][2], q11[4][2], q10[4][2];
  #pragma unroll
  for (int m = 0; m < 4; ++m)
    #pragma unroll
    for (int n = 0; n < 2; ++n) {
      q00[m][n] = (f32x4){0.f, 0.f, 0.f, 0.f};
      q01[m][n] = (f32x4){0.f, 0.f, 0.f, 0.f};
      q11[m][n] = (f32x4){0.f, 0.f, 0.f, 0.f};
      q10[m][n] = (f32x4){0.f, 0.f, 0.f, 0.f};
    }
  short8 av[4][2], bvlo[2][2], bvhi[2][2];

  // prologue: mimic steady-state tail (Blo0,Bhi0,Alo0,Ahi0,Blo1,Bhi1); Alo1/Ahi1 at ph1/ph2
  stB(0, 0, 0); stB(0, 1, 0); stA(0, 0, 0); stA(0, 1, 0);
  stB(1, 0, 64); stB(1, 1, 64);
  VW4;
  BAR;

  int niter = K >> 7;
  for (int it = 0; it < niter; ++it) {
    int kt0 = it << 7;
    int ktn0 = (it + 1 < niter) ? (kt0 + 128) : kt0;
    int ktn1 = ktn0 + 64;
    // ---- buf0 (K-tile kt0) ----
    LOAD_A(0, 0); LOAD_B(bvlo, 0, 0);
    stA(1, 0, kt0 + 64);
    BAR; PH_MFMA(q00, bvlo); BAR;
    LOAD_B(bvhi, 0, 1);
    stA(1, 1, kt0 + 64);
    BAR; PH_MFMA(q01, bvhi); BAR;
    LOAD_A(0, 1);
    stB(0, 0, ktn0);
    BAR; PH_MFMA(q11, bvhi); BAR;
    stB(0, 1, ktn0);
    VW4;
    BAR; PH_MFMA(q10, bvlo); BAR;
    // ---- buf1 (K-tile kt0+64) ----
    LOAD_A(1, 0); LOAD_B(bvlo, 1, 0);
    stA(0, 0, ktn0);
    BAR; PH_MFMA(q00, bvlo); BAR;
    LOAD_B(bvhi, 1, 1);
    stA(0, 1, ktn0);
    BAR; PH_MFMA(q01, bvhi); BAR;
    LOAD_A(1, 1);
    stB(1, 0, ktn1);
    BAR; PH_MFMA(q11, bvhi); BAR;
    stB(1, 1, ktn1);
    VW4;
    BAR; PH_MFMA(q10, bvlo); BAR;
  }

  int crow = kq * 4;   // C/D: col=lane&15, row=(lane>>4)*4+reg
  int ccol = fr;
  const float* be = bias + (size_t)e * N;
  EPI(q00, 0, 0); EPI(q01, 0, 32); EPI(q11, 64, 32); EPI(q10, 64, 0);
}

// ---- K7: combine — one wave per token: out[t] = g0*eo[s0] + g1*eo[s1] ----
__global__ void __launch_bounds__(256) combine_out(
    const float* __restrict__ eo, const int* __restrict__ tslot,
    const float* __restrict__ g01, float* __restrict__ out) {
  int wave = threadIdx.x >> 6, lane = threadIdx.x & 63;
  int tok = blockIdx.x * 4 + wave;
  int s0 = tslot[tok * 2 + 0], s1 = tslot[tok * 2 + 1];
  float g0 = g01[tok * 2 + 0], g1 = g01[tok * 2 + 1];
  const float* r0 = eo + (size_t)s0 * DOUT + lane * 8;
  const float* r1 = eo + (size_t)s1 * DOUT + lane * 8;
  float* o = out + (size_t)tok * DOUT + lane * 8;
  #pragma unroll
  for (int j = 0; j < 2; ++j) {
    float4 v0 = ((const float4*)r0)[j];
    float4 v1 = ((const float4*)r1)[j];
    float4 ov;
    ov.x = g0 * v0.x + g1 * v1.x;
    ov.y = g0 * v0.y + g1 * v1.y;
    ov.z = g0 * v0.z + g1 * v1.z;
    ov.w = g0 * v0.w + g1 * v1.w;
    ((float4*)o)[j] = ov;
  }
}

extern "C" void kernel_launch(void* const* d_in, const int* in_sizes, int n_in,
                              void* d_out, int out_size, void* d_ws, size_t ws_size,
                              hipStream_t stream) {
  const float* x   = (const float*)d_in[0];
  const float* Wr  = (const float*)d_in[1];
  const float* br  = (const float*)d_in[2];
  const float* emb = (const float*)d_in[3];
  const float* W1  = (const float*)d_in[4];
  const float* b1  = (const float*)d_in[5];
  const float* W2  = (const float*)d_in[6];
  const float* b2  = (const float*)d_in[7];
  const float* W3  = (const float*)d_in[8];
  const float* b3  = (const float*)d_in[9];
  float* out = (float*)d_out;
  char* ws = (char*)d_ws;

  float* P      = (float*)(ws + OFF_P);
  float* c      = (float*)(ws + OFF_C);
  int*   counts = (int*)(ws + OFF_CTRL);
  int*   poff   = (int*)(ws + OFF_CTRL + 128);
  int*   e01    = (int*)(ws + OFF_E01);
  float* g01    = (float*)(ws + OFF_G01);
  int*   gtok   = (int*)(ws + OFF_GTOK);
  float* ggate  = (float*)(ws + OFF_GGATE);
  int*   tslot  = (int*)(ws + OFF_TSLOT);
  int*   bhist  = (int*)(ws + OFF_BH);
  int*   bbase  = (int*)(ws + OFF_BB);
  u16*   W1T    = (u16*)(ws + OFF_W1T);
  u16*   W2T    = (u16*)(ws + OFF_W2T);
  u16*   W3T    = (u16*)(ws + OFF_W3T);
  u16*   xbf    = (u16*)(ws + OFF_XBF);
  u16*   h1     = (u16*)(ws + OFF_H1);
  u16*   h2     = (u16*)(ws + OFF_H2);
  float* eo     = (float*)(ws + OFF_EO);

  conv_w<DIN, H1N><<<dim3(H1N / 64, DIN / 64, NE), 256, 0, stream>>>(W1, W1T);
  conv_w<H1N, H2N><<<dim3(H2N / 64, H1N / 64, NE), 256, 0, stream>>>(W2, W2T);
  conv_w<H2N, DOUT><<<dim3(DOUT / 64, H2N / 64, NE), 256, 0, stream>>>(W3, W3T);

  router_prep<<<64, 256, 0, stream>>>(Wr, br, emb, P, c);
  router_score<<<RBLK, 256, 0, stream>>>(x, P, c, e01, g01, bhist, xbf);
  scan_offsets<<<1, 1024, 0, stream>>>(bhist, counts, poff, bbase, gtok);
  build_lists<<<RBLK, 64, 0, stream>>>(e01, g01, bbase, gtok, ggate, tslot);

  int nb1 = (H1N >> 8) * (CAP / 256);   // 4*144 = 576
  int nb2 = (H2N >> 8) * (CAP / 256);   // 2*144 = 288
  int nb3 = (DOUT >> 8) * (CAP / 256);  // 2*144 = 288
  gemm_moe256<0, true><<<nb1, 512, 0, stream>>>(xbf, W1T, b1, h1, nullptr,
                                                poff, gtok, DIN, H1N, nb1);
  gemm_moe256<0, false><<<nb2, 512, 0, stream>>>(h1, W2T, b2, h2, nullptr,
                                                 poff, nullptr, H1N, H2N, nb2);
  gemm_moe256<2, false><<<nb3, 512, 0, stream>>>(h2, W3T, b3, nullptr, eo,
                                                 poff, nullptr, H2N, DOUT, nb3);
  combine_out<<<N_TOK / 4, 256, 0, stream>>>(eo, tslot, g01, out);
}

// Round 13
// 280.024 us; speedup vs baseline: 1.1818x; 1.1818x over previous
//
#include <hip/hip_runtime.h>

typedef unsigned short u16;
typedef __attribute__((ext_vector_type(8))) short short8;
typedef __attribute__((ext_vector_type(8))) unsigned short ush8;
typedef __attribute__((ext_vector_type(4))) float f32x4;

#define N_TOK 16384
#define DIN   1024
#define NE    16
#define DEMB  128
#define H1N   1024
#define H2N   512
#define DOUT  512
#define CAP   34816   // 32768 entries + 16*128 padding
#define MT    (CAP/128)
#define RBLK  1024    // router blocks (16 tokens each)

// ---- workspace layout (bytes), ends 200,098,304 (< proven 201.9 MB) ----
#define OFF_P      0ul           // 65536
#define OFF_C      65536ul       // 256
#define OFF_CTRL   65792ul       // counts[16]@0, poff[17]@128 (256)
#define OFF_E01    66048ul       // 131072
#define OFF_G01    197120ul      // 131072
#define OFF_GTOK   328192ul      // CAP*4 = 139264
#define OFF_GGATE  467456ul      // 139264
#define OFF_TSLOT  606720ul      // N_TOK*2*4 = 131072
#define OFF_BH     737792ul      // 65536
#define OFF_BB     803328ul      // 65536
#define OFF_W1T    868864ul      // 33554432
#define OFF_W2T    34423296ul    // 16777216
#define OFF_W3T    51200512ul    // 8388608
#define OFF_XBF    59589120ul    // N_TOK*1024*2 = 33554432
#define OFF_H1     93143552ul    // CAP*1024*2 = 71303168
#define OFF_H2     164446720ul   // CAP*512*2  = 35651584
#define OFF_EO     OFF_H1        // eo bf16 CAP*512*2 = 35651584 (h1 dead after L2)

__device__ __forceinline__ u16 f2bf(float f) {
  union { float f; unsigned u; } v; v.f = f;
  unsigned r = v.u + 0x7fff + ((v.u >> 16) & 1);   // RNE, finite inputs
  return (u16)(r >> 16);
}

__device__ __forceinline__ float bf2f(u16 b) {
  union { unsigned u; float f; } v; v.u = ((unsigned)b) << 16;
  return v.f;
}

__device__ __forceinline__ void async_copy16(const u16* g, u16* l) {
  __builtin_amdgcn_global_load_lds((const __attribute__((address_space(1))) unsigned*)g,
                                   (__attribute__((address_space(3))) unsigned*)l,
                                   16, 0, 0);
}

// ---- K0: P = 2*Wr@emb^T [1024][16], c_e = 2*br.emb_e - |emb_e|^2 ----
__global__ void router_prep(const float* __restrict__ Wr, const float* __restrict__ br,
                            const float* __restrict__ emb, float* __restrict__ P,
                            float* __restrict__ c) {
  int idx = blockIdx.x * 256 + threadIdx.x;
  int row = idx >> 4, e = idx & 15;
  float s = 0.f;
  for (int j = 0; j < DEMB; ++j) s += Wr[row * DEMB + j] * emb[e * DEMB + j];
  P[row * NE + e] = 2.f * s;
  if (idx < NE) {
    float cc = 0.f, n2 = 0.f;
    for (int j = 0; j < DEMB; ++j) {
      float ev = emb[idx * DEMB + j];
      cc += br[j] * ev;
      n2 += ev * ev;
    }
    c[idx] = 2.f * cc - n2;
  }
}

// ---- K1: scores, top-2, gates; per-block LDS histogram -> bhist; xbf emit ----
__global__ void __launch_bounds__(256) router_score(
    const float* __restrict__ x, const float* __restrict__ P,
    const float* __restrict__ c, int* __restrict__ e01,
    float* __restrict__ g01, int* __restrict__ bhist,
    u16* __restrict__ xbf) {
  __shared__ float xs[16384];
  __shared__ int lh[16];
  int wave = threadIdx.x >> 6, lane = threadIdx.x & 63;
  int e2 = lane & 7, kgl = lane >> 3;
  int tbase = blockIdx.x * 16 + wave * 4;
  float* xw = xs + wave * 4096;

  if (threadIdx.x < 16) lh[threadIdx.x] = 0;

  u16* xbrow = xbf + (size_t)tbase * DIN;
  #pragma unroll
  for (int t = 0; t < 4; ++t) {
    const float* src = x + (size_t)(tbase + t) * DIN;
    #pragma unroll
    for (int q = 0; q < 4; ++q) {
      int g = q * 256 + lane * 4;
      float4 v = *(const float4*)(src + g);
      *(float4*)(xw + t * 1024 + g) = v;
      ushort4 o;
      o.x = f2bf(v.x); o.y = f2bf(v.y); o.z = f2bf(v.z); o.w = f2bf(v.w);
      *(ushort4*)(xbrow + t * DIN + g) = o;
    }
  }
  __syncthreads();

  int te0 = 2 * e2, te1 = te0 + 1;
  float ce0 = c[te0], ce1 = c[te1];
  const float* Pb = P + te0;

  float acc0[4] = {0.f, 0.f, 0.f, 0.f};
  float acc1[4] = {0.f, 0.f, 0.f, 0.f};
  int cbase = kgl * 128;
  #pragma unroll 4
  for (int i = 0; i < 32; ++i) {
    int w = (kgl * 4 + i * 4) & 127;
    int idx = cbase + w;
    float2 pv0 = *(const float2*)(Pb + (size_t)(idx + 0) * NE);
    float2 pv1 = *(const float2*)(Pb + (size_t)(idx + 1) * NE);
    float2 pv2 = *(const float2*)(Pb + (size_t)(idx + 2) * NE);
    float2 pv3 = *(const float2*)(Pb + (size_t)(idx + 3) * NE);
    #pragma unroll
    for (int t = 0; t < 4; ++t) {
      float4 xv = *(const float4*)(xw + t * 1024 + idx);
      acc0[t] = fmaf(xv.x, pv0.x, acc0[t]); acc1[t] = fmaf(xv.x, pv0.y, acc1[t]);
      acc0[t] = fmaf(xv.y, pv1.x, acc0[t]); acc1[t] = fmaf(xv.y, pv1.y, acc1[t]);
      acc0[t] = fmaf(xv.z, pv2.x, acc0[t]); acc1[t] = fmaf(xv.z, pv2.y, acc1[t]);
      acc0[t] = fmaf(xv.w, pv3.x, acc0[t]); acc1[t] = fmaf(xv.w, pv3.y, acc1[t]);
    }
  }

  for (int t = 0; t < 4; ++t) {
    float s0 = acc0[t], s1 = acc1[t];
    #pragma unroll
    for (int off = 8; off <= 32; off <<= 1) {
      s0 += __shfl_xor(s0, off);
      s1 += __shfl_xor(s1, off);
    }
    s0 += ce0; s1 += ce1;
    float hi; int hidx;
    if (s0 >= s1) { hi = s0; hidx = te0; } else { hi = s1; hidx = te1; }
    float m1 = hi; int i1 = hidx;
    #pragma unroll
    for (int off = 1; off < 8; off <<= 1) {
      float so = __shfl_xor(m1, off); int io = __shfl_xor(i1, off);
      if (so > m1 || (so == m1 && io < i1)) { m1 = so; i1 = io; }
    }
    float c2; int c2i;
    if (i1 == te0)      { c2 = s1; c2i = te1; }
    else if (i1 == te1) { c2 = s0; c2i = te0; }
    else                { c2 = hi; c2i = hidx; }
    float m2 = c2; int i2 = c2i;
    #pragma unroll
    for (int off = 1; off < 8; off <<= 1) {
      float so = __shfl_xor(m2, off); int io = __shfl_xor(i2, off);
      if (so > m2 || (so == m2 && io < i2)) { m2 = so; i2 = io; }
    }
    if (lane == 0) {
      int tok = tbase + t;
      float ev = expf(m2 - m1);
      float inv = 1.f / (1.f + ev);
      e01[tok * 2 + 0] = i1; e01[tok * 2 + 1] = i2;
      g01[tok * 2 + 0] = inv; g01[tok * 2 + 1] = ev * inv;
      atomicAdd(&lh[i1], 1);
      atomicAdd(&lh[i2], 1);
    }
  }
  __syncthreads();
  if (threadIdx.x < 16) bhist[blockIdx.x * 16 + threadIdx.x] = lh[threadIdx.x];
}

// ---- K2: scan bhist -> counts, poff, per-block bases; zero-fill gtok pads ----
__global__ void __launch_bounds__(1024) scan_offsets(
    const int* __restrict__ bhist, int* __restrict__ counts,
    int* __restrict__ poff, int* __restrict__ bbase, int* __restrict__ gtok) {
  int t = threadIdx.x;
  int e = t & 15, ch = t >> 4;
  int b0 = ch * 16;
  int s = 0;
  #pragma unroll
  for (int i = 0; i < 16; ++i) s += bhist[(b0 + i) * 16 + e];
  __shared__ int part[64][16];
  __shared__ int chbase[64][16];
  __shared__ int cnt[16];
  __shared__ int pof[16];
  part[ch][e] = s;
  __syncthreads();
  if (t < 16) {
    int run = 0;
    for (int c2 = 0; c2 < 64; ++c2) { chbase[c2][t] = run; run += part[c2][t]; }
    cnt[t] = run;
  }
  __syncthreads();
  if (t == 0) {
    int off = 0;
    for (int e2 = 0; e2 < NE; ++e2) {
      pof[e2] = off;
      poff[e2] = off;
      counts[e2] = cnt[e2];
      off += (cnt[e2] + 127) & ~127;
    }
    poff[NE] = off;
  }
  __syncthreads();
  // zero-fill intra-expert pad slots of gtok (GEMM indirection reads them; token 0 safe)
  int padc = ((cnt[e] + 127) & ~127) - cnt[e];
  int pbase = pof[e] + cnt[e];
  if (ch < padc) gtok[pbase + ch] = 0;
  if (ch + 64 < padc) gtok[pbase + ch + 64] = 0;

  int run = pof[e] + chbase[ch][e];
  #pragma unroll
  for (int i = 0; i < 16; ++i) {
    bbase[(b0 + i) * 16 + e] = run;
    run += bhist[(b0 + i) * 16 + e];
  }
}

// ---- K3: CSR entry lists + inverse map tslot[t*2+k] = slot ----
__global__ void build_lists(const int* __restrict__ e01, const float* __restrict__ g01,
                            const int* __restrict__ bbase, int* __restrict__ gtok,
                            float* __restrict__ ggate, int* __restrict__ tslot) {
  __shared__ int pos[16];
  int tid = threadIdx.x;
  if (tid < 16) pos[tid] = bbase[blockIdx.x * 16 + tid];
  __syncthreads();
  if (tid < 16) {
    int t = blockIdx.x * 16 + tid;
    #pragma unroll
    for (int k = 0; k < 2; ++k) {
      int e = e01[t * 2 + k];
      int p = atomicAdd(&pos[e], 1);
      gtok[p] = t;
      ggate[p] = g01[t * 2 + k];
      tslot[t * 2 + k] = p;
    }
  }
}

// ---- K5: weight convert+transpose: [E][K][N] f32 -> [E][N][K] bf16 ----
// Vectorized: float4 reads (1 KB/wave-instr), LDS transpose, ushort8 x2 writes
// (16 B/lane; wave writes 16 rows x 128 B). LDS banks <=2-way both sides (free).
template<int K, int N>
__global__ void __launch_bounds__(256) conv_w(const float* __restrict__ W,
                                              u16* __restrict__ WT) {
  __shared__ float tile[64][65];
  int e = blockIdx.z;
  int n0 = blockIdx.x * 64, k0 = blockIdx.y * 64;
  int tid = threadIdx.x;
  const float* Wb = W + (size_t)e * K * N;
  int kr = tid >> 4, nc = (tid & 15) * 4;
  #pragma unroll
  for (int p = 0; p < 4; ++p) {
    int k = p * 16 + kr;
    float4 v = *(const float4*)(Wb + (size_t)(k0 + k) * N + n0 + nc);
    tile[k][nc + 0] = v.x;
    tile[k][nc + 1] = v.y;
    tile[k][nc + 2] = v.z;
    tile[k][nc + 3] = v.w;
  }
  __syncthreads();
  int n = tid >> 2, kc = (tid & 3) * 16;
  ush8 o0, o1;
  #pragma unroll
  for (int j = 0; j < 8; ++j) {
    o0[j] = f2bf(tile[kc + j][n]);
    o1[j] = f2bf(tile[kc + 8 + j][n]);
  }
  u16* dst = WT + (size_t)e * N * K + (size_t)(n0 + n) * K + k0 + kc;
  *(ush8*)dst = o0;
  *(ush8*)(dst + 8) = o1;
}

// ---- GEMM: A x B_e (both K-contig bf16), r9-proven structure ----
// T4 counted-vmcnt, 3-buffer rotation (r9-verified). INDIR: A-rows via gtok.
// MODE 0: Cb = bf16(relu(acc+bias)); MODE 2: Cb = bf16(acc+bias) (no relu)
template<int MODE, bool INDIR>
__global__ void __launch_bounds__(256)
gemm_moe(const u16* __restrict__ A, const u16* __restrict__ Ball,
         const float* __restrict__ bias, u16* __restrict__ Cb,
         const int* __restrict__ poff, const int* __restrict__ counts,
         const int* __restrict__ gtok, int K, int N, int nblk) {
  __shared__ u16 Asm[3][4096];
  __shared__ u16 Bsm[3][4096];

  int bid = blockIdx.x;
  int q = nblk >> 3, r = nblk & 7;
  int xcd = bid & 7, sidx = bid >> 3;
  int wg = (xcd < r ? xcd * (q + 1) : r * (q + 1) + (xcd - r) * q) + sidx;
  int NB = N >> 7;
  int rb = wg / NB, nb = wg - rb * NB;

  int row_base = rb * 128;
  if (row_base >= poff[NE]) return;
  int e = 0;
  while (row_base >= poff[e + 1]) ++e;

  int tid = threadIdx.x;
  int wave = tid >> 6, lane = tid & 63;
  int wm = wave >> 1, wn = wave & 1;
  int fr = lane & 15, kq = lane >> 4;
  int n_base = nb * 128;

  const u16* Brow = Ball + (size_t)e * N * K + (size_t)n_base * K;

  int rr0 = tid >> 2, rr1 = rr0 + 64;
  int ch8 = ((tid & 3) ^ ((rr0 >> 1) & 3)) * 8;
  const u16 *a0, *a1;
  if constexpr (INDIR) {
    a0 = A + (size_t)gtok[row_base + rr0] * K;
    a1 = A + (size_t)gtok[row_base + rr1] * K;
  } else {
    a0 = A + (size_t)(row_base + rr0) * K;
    a1 = A + (size_t)(row_base + rr1) * K;
  }
  const u16* b0 = Brow + (size_t)rr0 * K;
  const u16* b1 = Brow + (size_t)rr1 * K;

  f32x4 acc[4][4];
  #pragma unroll
  for (int m = 0; m < 4; ++m)
    #pragma unroll
    for (int n = 0; n < 4; ++n)
      acc[m][n] = (f32x4){0.f, 0.f, 0.f, 0.f};

  int swz = (fr >> 1) & 3;

  auto stage_tile = [&](int buf, int kt) {
    async_copy16(a0 + kt + ch8, &Asm[buf][tid * 8]);
    async_copy16(a1 + kt + ch8, &Asm[buf][(256 + tid) * 8]);
    async_copy16(b0 + kt + ch8, &Bsm[buf][tid * 8]);
    async_copy16(b1 + kt + ch8, &Bsm[buf][(256 + tid) * 8]);
  };

  // prologue: tiles 0,1 in flight
  stage_tile(0, 0);
  stage_tile(1, 32);

  int nstep = K >> 5;
  int rd = 0, st = 2;
  for (int s = 0; s < nstep; ++s) {
    if (s == nstep - 1)
      asm volatile("s_waitcnt vmcnt(0)\n\ts_barrier" ::: "memory");
    else
      asm volatile("s_waitcnt vmcnt(4)\n\ts_barrier" ::: "memory");
    if (s + 2 < nstep) stage_tile(st, (s + 2) << 5);
    short8 av[4], bv[4];
    #pragma unroll
    for (int m = 0; m < 4; ++m)
      av[m] = *(const short8*)(&Asm[rd][((wm * 64 + m * 16 + fr) * 4 + (kq ^ swz)) * 8]);
    #pragma unroll
    for (int n = 0; n < 4; ++n)
      bv[n] = *(const short8*)(&Bsm[rd][((wn * 64 + n * 16 + fr) * 4 + (kq ^ swz)) * 8]);
    #pragma unroll
    for (int m = 0; m < 4; ++m)
      #pragma unroll
      for (int n = 0; n < 4; ++n)
        acc[m][n] = __builtin_amdgcn_mfma_f32_16x16x32_bf16(av[m], bv[n], acc[m][n], 0, 0, 0);
    rd = rd == 2 ? 0 : rd + 1;
    st = st == 2 ? 0 : st + 1;
  }

  int crow = (lane >> 4) * 4;   // C/D: col=lane&15, row=(lane>>4)*4+reg
  int ccol = lane & 15;
  const float* be = bias + (size_t)e * N;
  #pragma unroll
  for (int m = 0; m < 4; ++m) {
    int gr0 = row_base + wm * 64 + m * 16 + crow;
    #pragma unroll
    for (int n = 0; n < 4; ++n) {
      int gc = n_base + wn * 64 + n * 16 + ccol;
      float bvs = be[gc];
      #pragma unroll
      for (int r2 = 0; r2 < 4; ++r2) {
        float v = acc[m][n][r2] + bvs;
        if constexpr (MODE == 0) v = v > 0.f ? v : 0.f;
        Cb[(size_t)(gr0 + r2) * N + gc] = f2bf(v);
      }
    }
  }
}

// ---- K7: combine — one wave per token: out[t] = g0*eo[s0] + g1*eo[s1] (eo bf16) ----
__global__ void __launch_bounds__(256) combine_out(
    const u16* __restrict__ eo, const int* __restrict__ tslot,
    const float* __restrict__ g01, float* __restrict__ out) {
  int wave = threadIdx.x >> 6, lane = threadIdx.x & 63;
  int tok = blockIdx.x * 4 + wave;
  int s0 = tslot[tok * 2 + 0], s1 = tslot[tok * 2 + 1];
  float g0 = g01[tok * 2 + 0], g1 = g01[tok * 2 + 1];
  ush8 v0 = *(const ush8*)(eo + (size_t)s0 * DOUT + lane * 8);
  ush8 v1 = *(const ush8*)(eo + (size_t)s1 * DOUT + lane * 8);
  float* o = out + (size_t)tok * DOUT + lane * 8;
  float4 ov0, ov1;
  ov0.x = g0 * bf2f(v0[0]) + g1 * bf2f(v1[0]);
  ov0.y = g0 * bf2f(v0[1]) + g1 * bf2f(v1[1]);
  ov0.z = g0 * bf2f(v0[2]) + g1 * bf2f(v1[2]);
  ov0.w = g0 * bf2f(v0[3]) + g1 * bf2f(v1[3]);
  ov1.x = g0 * bf2f(v0[4]) + g1 * bf2f(v1[4]);
  ov1.y = g0 * bf2f(v0[5]) + g1 * bf2f(v1[5]);
  ov1.z = g0 * bf2f(v0[6]) + g1 * bf2f(v1[6]);
  ov1.w = g0 * bf2f(v0[7]) + g1 * bf2f(v1[7]);
  ((float4*)o)[0] = ov0;
  ((float4*)o)[1] = ov1;
}

extern "C" void kernel_launch(void* const* d_in, const int* in_sizes, int n_in,
                              void* d_out, int out_size, void* d_ws, size_t ws_size,
                              hipStream_t stream) {
  const float* x   = (const float*)d_in[0];
  const float* Wr  = (const float*)d_in[1];
  const float* br  = (const float*)d_in[2];
  const float* emb = (const float*)d_in[3];
  const float* W1  = (const float*)d_in[4];
  const float* b1  = (const float*)d_in[5];
  const float* W2  = (const float*)d_in[6];
  const float* b2  = (const float*)d_in[7];
  const float* W3  = (const float*)d_in[8];
  const float* b3  = (const float*)d_in[9];
  float* out = (float*)d_out;
  char* ws = (char*)d_ws;

  float* P      = (float*)(ws + OFF_P);
  float* c      = (float*)(ws + OFF_C);
  int*   counts = (int*)(ws + OFF_CTRL);
  int*   poff   = (int*)(ws + OFF_CTRL + 128);
  int*   e01    = (int*)(ws + OFF_E01);
  float* g01    = (float*)(ws + OFF_G01);
  int*   gtok   = (int*)(ws + OFF_GTOK);
  float* ggate  = (float*)(ws + OFF_GGATE);
  int*   tslot  = (int*)(ws + OFF_TSLOT);
  int*   bhist  = (int*)(ws + OFF_BH);
  int*   bbase  = (int*)(ws + OFF_BB);
  u16*   W1T    = (u16*)(ws + OFF_W1T);
  u16*   W2T    = (u16*)(ws + OFF_W2T);
  u16*   W3T    = (u16*)(ws + OFF_W3T);
  u16*   xbf    = (u16*)(ws + OFF_XBF);
  u16*   h1     = (u16*)(ws + OFF_H1);
  u16*   h2     = (u16*)(ws + OFF_H2);
  u16*   eo16   = (u16*)(ws + OFF_EO);

  conv_w<DIN, H1N><<<dim3(H1N / 64, DIN / 64, NE), 256, 0, stream>>>(W1, W1T);
  conv_w<H1N, H2N><<<dim3(H2N / 64, H1N / 64, NE), 256, 0, stream>>>(W2, W2T);
  conv_w<H2N, DOUT><<<dim3(DOUT / 64, H2N / 64, NE), 256, 0, stream>>>(W3, W3T);

  router_prep<<<64, 256, 0, stream>>>(Wr, br, emb, P, c);
  router_score<<<RBLK, 256, 0, stream>>>(x, P, c, e01, g01, bhist, xbf);
  scan_offsets<<<1, 1024, 0, stream>>>(bhist, counts, poff, bbase, gtok);
  build_lists<<<RBLK, 64, 0, stream>>>(e01, g01, bbase, gtok, ggate, tslot);

  int nb1 = (H1N / 128) * MT;
  int nb2 = (H2N / 128) * MT;
  int nb3 = (DOUT / 128) * MT;
  gemm_moe<0, true><<<nb1, 256, 0, stream>>>(xbf, W1T, b1, h1,
                                             poff, counts, gtok, DIN, H1N, nb1);
  gemm_moe<0, false><<<nb2, 256, 0, stream>>>(h1, W2T, b2, h2,
                                              poff, counts, nullptr, H1N, H2N, nb2);
  gemm_moe<2, false><<<nb3, 256, 0, stream>>>(h2, W3T, b3, eo16,
                                              poff, counts, nullptr, H2N, DOUT, nb3);
  combine_out<<<N_TOK / 4, 256, 0, stream>>>(eo16, tslot, g01, out);
}